// Round 1
// baseline (209.155 us; speedup 1.0000x reference)
//
#include <hip/hip_runtime.h>

#define NB 8
#define L_TOT 4096
#define DIM 256
#define HEADS 8
#define HEAD_DIM 32
#define M_TOT 512
#define SCALE 0.17677669529663687f   // 32^-0.5

typedef float f32x16 __attribute__((ext_vector_type(16)));
typedef short bf16x8 __attribute__((ext_vector_type(8)));

__device__ __forceinline__ unsigned short f2bf(float x) {
    union { float f; unsigned u; } un; un.f = x;
    return (unsigned short)((un.u + 0x7FFFu + ((un.u >> 16) & 1u)) >> 16);
}

// 16B bf16 fragment from LDS as 2x8B (pointers are only 8B-aligned)
__device__ __forceinline__ bf16x8 ld_bf8_lds(const unsigned short* p) {
    union { uint2 u[2]; bf16x8 v; } r;
    r.u[0] = *(const uint2*)(p);
    r.u[1] = *(const uint2*)(p + 4);
    return r.v;
}

// k_sum[bh][m][c] = sum_hq k[b, hq*512+m, head*32+c]  -> bf16 in ws
__global__ __launch_bounds__(256) void ksum_kernel(const float* __restrict__ k,
                                                   unsigned short* __restrict__ ks) {
    const int bh = blockIdx.x >> 3;
    const int part = blockIdx.x & 7;
    const int b = bh >> 3, head = bh & 7;
    const float* kb = k + (size_t)b * L_TOT * DIM + head * HEAD_DIM;
    for (int idx = threadIdx.x; idx < 64 * 32; idx += 256) {
        const int m = part * 64 + (idx >> 5), c = idx & 31;
        float s = 0.f;
#pragma unroll
        for (int hq = 0; hq < 8; ++hq)
            s += kb[(size_t)(hq * 512 + m) * DIM + c];
        ks[(size_t)bh * (M_TOT * HEAD_DIM) + (size_t)m * 32 + c] = f2bf(s);
    }
}

// One block per (bh, h). 8 waves; each wave does 2 groups of 32 q-rows.
// S^T = mfma(k_sum, q): lane holds qrow = lane&31, 16 m-values (+4*(lane>>5)).
// Online softmax over 16 chunks of 32 m; P staged via wave-private LDS;
// O^T = mfma(vT, P) accumulated in regs; normalized; fp32 store.
template <bool USE_WS>
__global__ __launch_bounds__(512) void attn_kernel(const float* __restrict__ q,
                                                   const float* __restrict__ kg,
                                                   const float* __restrict__ v,
                                                   const unsigned short* __restrict__ ks,
                                                   float* __restrict__ out) {
    // USE_WS:  vT[32][516] (16512) + 8 * P[32][36] (9216)
    // !USE_WS: KS[512][36] (18432) + 8 * P[32][36] (9216)
    __shared__ unsigned short smem[USE_WS ? (16512 + 8 * 1152) : (18432 + 8 * 1152)];
    const int tid = threadIdx.x;
    const int wave = tid >> 6;
    const int lane = tid & 63;
    const int ql = lane & 31;
    const int hi = lane >> 5;
    const int bh = blockIdx.x >> 3, h = blockIdx.x & 7;
    const int b = bh >> 3, head = bh & 7;

    const float* vbase = v + ((size_t)b * L_TOT + h * M_TOT) * DIM + head * HEAD_DIM;
    unsigned short* P = smem + (USE_WS ? 16512 : 18432) + wave * 1152;

    if (USE_WS) {
        unsigned short* vT = smem;  // vT[c][m], stride 516 (2-way-free banks)
        for (int idx = tid; idx < M_TOT * HEAD_DIM; idx += 512) {
            const int m = idx >> 5, c = idx & 31;
            vT[c * 516 + m] = f2bf(vbase[(size_t)m * DIM + c]);
        }
    } else {
        unsigned short* KS = smem;  // k_sum[m][c], stride 36
        const float* kb = kg + (size_t)b * L_TOT * DIM + head * HEAD_DIM;
        for (int idx = tid; idx < M_TOT * HEAD_DIM; idx += 512) {
            const int m = idx >> 5, c = idx & 31;
            float s = 0.f;
#pragma unroll
            for (int hq = 0; hq < 8; ++hq)
                s += kb[(size_t)(hq * 512 + m) * DIM + c];
            KS[m * 36 + c] = f2bf(s);
        }
    }
    __syncthreads();

    const float* qbase = q + (size_t)b * L_TOT * DIM + head * HEAD_DIM;
    float* obase = out + (size_t)b * L_TOT * DIM + head * HEAD_DIM;

    for (int gi = 0; gi < 2; ++gi) {
        const int g = wave * 2 + gi;
        const int w = g >> 1, n0 = (g & 1) * 32;
        const int n = n0 + ql;
        const int Lrow = (h * 8 + (n >> 3)) * 64 + w * 8 + (n & 7);

        // q B-fragments: col = qrow = ql, k(c) = 16*half + 8*hi + j
        bf16x8 qf[2];
        {
            const float* qp = qbase + (size_t)Lrow * DIM;
#pragma unroll
            for (int half = 0; half < 2; ++half) {
                const int c0 = 16 * half + 8 * hi;
                float4 f0 = *(const float4*)(qp + c0);
                float4 f1 = *(const float4*)(qp + c0 + 4);
                bf16x8 t;
                t[0] = (short)f2bf(f0.x * SCALE); t[1] = (short)f2bf(f0.y * SCALE);
                t[2] = (short)f2bf(f0.z * SCALE); t[3] = (short)f2bf(f0.w * SCALE);
                t[4] = (short)f2bf(f1.x * SCALE); t[5] = (short)f2bf(f1.y * SCALE);
                t[6] = (short)f2bf(f1.z * SCALE); t[7] = (short)f2bf(f1.w * SCALE);
                qf[half] = t;
            }
        }

        f32x16 O;
#pragma unroll
        for (int r = 0; r < 16; ++r) O[r] = 0.f;
        float mrun = -3.0e38f, lsum = 0.f;

        for (int ch = 0; ch < 16; ++ch) {
            const int M0 = ch * 32;
            f32x16 S;
#pragma unroll
            for (int r = 0; r < 16; ++r) S[r] = 0.f;
#pragma unroll
            for (int half = 0; half < 2; ++half) {
                bf16x8 A;  // A row = m = M0+ql, k(c) = 16*half + 8*hi + j
                if (USE_WS) {
                    A = *(const bf16x8*)(ks + ((size_t)bh * 512 + M0 + ql) * 32 + 16 * half + 8 * hi);
                } else {
                    const unsigned short* KS = smem;
                    A = ld_bf8_lds(KS + (M0 + ql) * 36 + 16 * half + 8 * hi);
                }
                S = __builtin_amdgcn_mfma_f32_32x32x16_bf16(A, qf[half], S, 0, 0, 0);
            }

            // online softmax: lane's 16 regs are m = (r&3)+8*(r>>2)+4*hi (+M0), col = qrow
            float cmax = S[0];
#pragma unroll
            for (int r = 1; r < 16; ++r) cmax = fmaxf(cmax, S[r]);
            cmax = fmaxf(cmax, __shfl_xor(cmax, 32, 64));
            const float mnew = fmaxf(mrun, cmax);
            const float alpha = __expf(mrun - mnew);
            float ps = 0.f;
            unsigned* Pw = (unsigned*)(P + ql * 36) + 2 * hi;
#pragma unroll
            for (int r8 = 0; r8 < 4; ++r8) {
                const float p0 = __expf(S[4 * r8 + 0] - mnew);
                const float p1 = __expf(S[4 * r8 + 1] - mnew);
                const float p2 = __expf(S[4 * r8 + 2] - mnew);
                const float p3 = __expf(S[4 * r8 + 3] - mnew);
                ps += (p0 + p1) + (p2 + p3);
                Pw[4 * r8]     = (unsigned)f2bf(p0) | ((unsigned)f2bf(p1) << 16);
                Pw[4 * r8 + 1] = (unsigned)f2bf(p2) | ((unsigned)f2bf(p3) << 16);
            }
            ps += __shfl_xor(ps, 32, 64);
            lsum = lsum * alpha + ps;
            mrun = mnew;
#pragma unroll
            for (int r = 0; r < 16; ++r) O[r] *= alpha;

            // PV: O^T[c_out][qrow] += sum_m vT[c_out][m] * P[m][qrow]
#pragma unroll
            for (int kt = 0; kt < 2; ++kt) {
                const int mk = M0 + 16 * kt + 8 * hi;
                bf16x8 Af;  // A row = c_out = ql, k(m) = mk + j
                if (USE_WS) {
                    const unsigned short* vT = smem;
                    Af = ld_bf8_lds(vT + ql * 516 + mk);
                } else {
                    bf16x8 t;
#pragma unroll
                    for (int j = 0; j < 8; ++j)
                        t[j] = (short)f2bf(vbase[(size_t)(mk + j) * DIM + ql]);
                    Af = t;
                }
                const bf16x8 Bf = ld_bf8_lds(P + ql * 36 + 16 * kt + 8 * hi);
                O = __builtin_amdgcn_mfma_f32_32x32x16_bf16(Af, Bf, O, 0, 0, 0);
            }
        }

        const float inv = 1.f / lsum;
        float* ob = obase + (size_t)Lrow * DIM;
#pragma unroll
        for (int r = 0; r < 16; ++r) {
            const int c = (r & 3) + 8 * (r >> 2) + 4 * hi;
            ob[c] = O[r] * inv;
        }
    }
}

extern "C" void kernel_launch(void* const* d_in, const int* in_sizes, int n_in,
                              void* d_out, int out_size, void* d_ws, size_t ws_size,
                              hipStream_t stream) {
    const float* qkv = (const float*)d_in[0];
    const float* q = qkv;
    const float* k = qkv + (size_t)NB * L_TOT * DIM;
    const float* v = qkv + (size_t)2 * NB * L_TOT * DIM;
    float* out = (float*)d_out;
    const size_t ks_bytes = (size_t)NB * HEADS * M_TOT * HEAD_DIM * 2;  // 2 MB
    if (ws_size >= ks_bytes) {
        unsigned short* ks = (unsigned short*)d_ws;
        ksum_kernel<<<dim3(512), dim3(256), 0, stream>>>(k, ks);
        attn_kernel<true><<<dim3(512), dim3(512), 0, stream>>>(q, k, v, ks, out);
    } else {
        attn_kernel<false><<<dim3(512), dim3(512), 0, stream>>>(q, k, v, nullptr, out);
    }
}

// Round 2
// 178.462 us; speedup vs baseline: 1.1720x; 1.1720x over previous
//
#include <hip/hip_runtime.h>
#include <hip/hip_bf16.h>

#define NB 8
#define L_TOT 4096
#define DIM 256
#define HEADS 8
#define HEAD_DIM 32
#define M_TOT 512
// softmax-scale folded with log2(e) so exp(x) == exp2(S)
#define QSCALE (0.17677669529663687f * 1.4426950408889634f)

typedef float f32x16 __attribute__((ext_vector_type(16)));
typedef short bf16x8 __attribute__((ext_vector_type(8)));

union BF8 { bf16x8 v; unsigned u[4]; uint2 u2[2]; };

// RNE packed f32x2 -> bf16x2 (lowers to v_cvt_pk_bf16_f32)
__device__ __forceinline__ unsigned cvt2(float lo, float hi) {
    __hip_bfloat162 h = __float22bfloat162_rn(make_float2(lo, hi));
    union { __hip_bfloat162 h2; unsigned u; } un;
    un.h2 = h;
    return un.u;
}

// k_sum[bh][m][c] = sum_hq k[b, hq*512+m, head*32+c]  -> bf16 in ws
__global__ __launch_bounds__(256) void ksum_kernel(const float* __restrict__ k,
                                                   unsigned short* __restrict__ ks) {
    const int blk = blockIdx.x;          // 1024 = bh(64) x part(16)
    const int bh = blk >> 4, part = blk & 15;
    const int b = bh >> 3, head = bh & 7;
    const float* kb = k + (size_t)b * L_TOT * DIM + head * HEAD_DIM;
    const int c0 = (threadIdx.x & 7) * 4;          // 4-float col group
    const int m = part * 32 + (threadIdx.x >> 3);  // [0,512)
    float4 s = make_float4(0.f, 0.f, 0.f, 0.f);
#pragma unroll
    for (int hq = 0; hq < 8; ++hq) {
        const float4 f = *(const float4*)(kb + (size_t)(hq * 512 + m) * DIM + c0);
        s.x += f.x; s.y += f.y; s.z += f.z; s.w += f.w;
    }
    uint2 o;
    o.x = cvt2(s.x, s.y);
    o.y = cvt2(s.z, s.w);
    *(uint2*)(ks + ((size_t)bh * M_TOT + m) * HEAD_DIM + c0) = o;
}

// One block per (bh, h, half). 8 waves, each wave owns 32 q-rows.
// S^T = mfma(ksum, q)  (lane = qrow), exp2 (no max-subtract), P->bf16 via
// cvt_pk + permlane32_swap (in-register), O = mfma(P, vT) accumulated fp32.
template <bool USE_WS>
__global__ __launch_bounds__(512, 8) void attn_kernel(const float* __restrict__ q,
                                                      const float* __restrict__ kg,
                                                      const float* __restrict__ v,
                                                      const unsigned short* __restrict__ ks,
                                                      float* __restrict__ out) {
    // vT[c][m] bf16, stride 516 (2-way-free banks); fallback adds KS[m][c] stride 36
    __shared__ unsigned short smem[USE_WS ? (32 * 516) : (32 * 516 + 512 * 36)];
    unsigned short* vT = smem;

    const int tid = threadIdx.x;
    const int wave = tid >> 6;
    const int lane = tid & 63;
    const int ql = lane & 31;
    const int hi = lane >> 5;

    // XCD-aware swizzle (1024 % 8 == 0 -> bijective)
    const int bid = blockIdx.x;
    const int wk = (bid & 7) * 128 + (bid >> 3);
    const int bh = wk >> 4, h = (wk >> 1) & 7, half = wk & 1;
    const int b = bh >> 3, head = bh & 7;

    const float* vbase = v + ((size_t)b * L_TOT + h * M_TOT) * DIM + head * HEAD_DIM;

    // ---- stage V transposed (bf16) ----
#pragma unroll
    for (int it = 0; it < 8; ++it) {
        const int idx = it * 512 + tid;      // [0, 4096)
        const int m = idx >> 3, c0 = (idx & 7) * 4;
        const float4 f = *(const float4*)(vbase + (size_t)m * DIM + c0);
        const unsigned w0 = cvt2(f.x, f.y), w1 = cvt2(f.z, f.w);
        vT[(c0 + 0) * 516 + m] = (unsigned short)w0;
        vT[(c0 + 1) * 516 + m] = (unsigned short)(w0 >> 16);
        vT[(c0 + 2) * 516 + m] = (unsigned short)w1;
        vT[(c0 + 3) * 516 + m] = (unsigned short)(w1 >> 16);
    }
    unsigned short* KS = smem + 32 * 516;
    if (!USE_WS) {
        const float* kb = kg + (size_t)b * L_TOT * DIM + head * HEAD_DIM;
        for (int idx = tid; idx < M_TOT * HEAD_DIM; idx += 512) {
            const int m = idx >> 5, c = idx & 31;
            float s = 0.f;
#pragma unroll
            for (int hq = 0; hq < 8; ++hq)
                s += kb[(size_t)(hq * 512 + m) * DIM + c];
            KS[m * 36 + c] = (unsigned short)cvt2(s, 0.f);
        }
    }
    __syncthreads();

    // ---- this wave's 32 q-rows ----
    const int g = half * 8 + wave;           // [0,16)
    const int wcol = g >> 1, n0 = (g & 1) * 32;
    const int n = n0 + ql;
    const int Lq = (h * 8 + (n >> 3)) * 64 + wcol * 8 + (n & 7);
    const float* qp = q + ((size_t)b * L_TOT + Lq) * DIM + head * HEAD_DIM;

    BF8 qf0, qf1;  // B-frag: col = qrow = ql, k(c) = 16*half_k + 8*hi + j
    {
        const float4 f0 = *(const float4*)(qp + 8 * hi);
        const float4 f1 = *(const float4*)(qp + 8 * hi + 4);
        qf0.u[0] = cvt2(f0.x * QSCALE, f0.y * QSCALE);
        qf0.u[1] = cvt2(f0.z * QSCALE, f0.w * QSCALE);
        qf0.u[2] = cvt2(f1.x * QSCALE, f1.y * QSCALE);
        qf0.u[3] = cvt2(f1.z * QSCALE, f1.w * QSCALE);
        const float4 f2 = *(const float4*)(qp + 16 + 8 * hi);
        const float4 f3 = *(const float4*)(qp + 16 + 8 * hi + 4);
        qf1.u[0] = cvt2(f2.x * QSCALE, f2.y * QSCALE);
        qf1.u[1] = cvt2(f2.z * QSCALE, f2.w * QSCALE);
        qf1.u[2] = cvt2(f3.x * QSCALE, f3.y * QSCALE);
        qf1.u[3] = cvt2(f3.z * QSCALE, f3.w * QSCALE);
    }

    const unsigned short* ksb = ks + (size_t)bh * M_TOT * HEAD_DIM;

    f32x16 O;
#pragma unroll
    for (int r = 0; r < 16; ++r) O[r] = 0.f;
    float lsum = 0.f;

    for (int ch = 0; ch < 16; ++ch) {
        const int M0 = ch << 5;
        f32x16 S;
#pragma unroll
        for (int r = 0; r < 16; ++r) S[r] = 0.f;

        BF8 A0, A1;  // A-frag: row = m = M0+ql, k(c) = 16*half_k + 8*hi + j
        if (USE_WS) {
            A0.v = *(const bf16x8*)(ksb + (size_t)(M0 + ql) * 32 + 8 * hi);
            A1.v = *(const bf16x8*)(ksb + (size_t)(M0 + ql) * 32 + 16 + 8 * hi);
        } else {
            const unsigned short* kr = KS + (M0 + ql) * 36 + 8 * hi;
            A0.u2[0] = *(const uint2*)(kr);
            A0.u2[1] = *(const uint2*)(kr + 4);
            A1.u2[0] = *(const uint2*)(kr + 16);
            A1.u2[1] = *(const uint2*)(kr + 20);
        }
        S = __builtin_amdgcn_mfma_f32_32x32x16_bf16(A0.v, qf0.v, S, 0, 0, 0);
        S = __builtin_amdgcn_mfma_f32_32x32x16_bf16(A1.v, qf1.v, S, 0, 0, 0);

        // p = exp2(S); lane's reg r is m = M0 + (r&3) + 8*(r>>2) + 4*hi, col = qrow
        float p[16];
#pragma unroll
        for (int r = 0; r < 16; ++r) p[r] = __builtin_amdgcn_exp2f(S[r]);
#pragma unroll
        for (int r = 0; r < 16; ++r) lsum += p[r];

        unsigned w0 = cvt2(p[0], p[1]),   w1 = cvt2(p[2], p[3]);
        unsigned w2 = cvt2(p[4], p[5]),   w3 = cvt2(p[6], p[7]);
        unsigned w4 = cvt2(p[8], p[9]),   w5 = cvt2(p[10], p[11]);
        unsigned w6 = cvt2(p[12], p[13]), w7 = cvt2(p[14], p[15]);
        // vdst.row1 <-> vsrc.row0: builds A-frag words (k = m ascending) in-register
        asm("v_permlane32_swap_b32 %0, %1" : "+v"(w0), "+v"(w2));
        asm("v_permlane32_swap_b32 %0, %1" : "+v"(w1), "+v"(w3));
        asm("v_permlane32_swap_b32 %0, %1" : "+v"(w4), "+v"(w6));
        asm("v_permlane32_swap_b32 %0, %1" : "+v"(w5), "+v"(w7));
        BF8 PA0, PA1, VB0, VB1;
        PA0.u[0] = w0; PA0.u[1] = w1; PA0.u[2] = w2; PA0.u[3] = w3;
        PA1.u[0] = w4; PA1.u[1] = w5; PA1.u[2] = w6; PA1.u[3] = w7;
        // V B-frag: col = c_out = ql, k(m) = M0 + 16*kt + 8*hi + j
        const unsigned short* vb = vT + ql * 516 + M0 + 8 * hi;
        VB0.u2[0] = *(const uint2*)(vb);
        VB0.u2[1] = *(const uint2*)(vb + 4);
        VB1.u2[0] = *(const uint2*)(vb + 16);
        VB1.u2[1] = *(const uint2*)(vb + 20);
        O = __builtin_amdgcn_mfma_f32_32x32x16_bf16(PA0.v, VB0.v, O, 0, 0, 0);
        O = __builtin_amdgcn_mfma_f32_32x32x16_bf16(PA1.v, VB1.v, O, 0, 0, 0);
    }

    // row-sum: own half + partner half
    lsum += __shfl_xor(lsum, 32, 64);
    const float inv = __builtin_amdgcn_rcpf(lsum);

    // O: col = c_out = ql, row(r) = qrow = (r&3) + 8*(r>>2) + 4*hi -> coalesced stores
    const int rowBase = h * 512 + (n0 >> 3) * 64 + wcol * 8 + 4 * hi;
    float* ob = out + ((size_t)b * L_TOT + rowBase) * DIM + head * HEAD_DIM + ql;
#pragma unroll
    for (int r = 0; r < 16; ++r) {
        const float iv = __shfl(inv, (r & 3) + 8 * (r >> 2) + 4 * hi, 64);
        ob[(size_t)((r >> 2) * 64 + (r & 3)) * DIM] = O[r] * iv;
    }
}

extern "C" void kernel_launch(void* const* d_in, const int* in_sizes, int n_in,
                              void* d_out, int out_size, void* d_ws, size_t ws_size,
                              hipStream_t stream) {
    const float* qkv = (const float*)d_in[0];
    const float* q = qkv;
    const float* k = qkv + (size_t)NB * L_TOT * DIM;
    const float* v = qkv + (size_t)2 * NB * L_TOT * DIM;
    float* out = (float*)d_out;
    const size_t ks_bytes = (size_t)NB * HEADS * M_TOT * HEAD_DIM * 2;  // 2 MB
    if (ws_size >= ks_bytes) {
        unsigned short* ks = (unsigned short*)d_ws;
        ksum_kernel<<<dim3(1024), dim3(256), 0, stream>>>(k, ks);
        attn_kernel<true><<<dim3(1024), dim3(512), 0, stream>>>(q, k, v, ks, out);
    } else {
        attn_kernel<false><<<dim3(1024), dim3(512), 0, stream>>>(q, k, v, nullptr, out);
    }
}

// Round 3
// 174.999 us; speedup vs baseline: 1.1952x; 1.0198x over previous
//
#include <hip/hip_runtime.h>
#include <hip/hip_bf16.h>

#define NB 8
#define L_TOT 4096
#define DIM 256
#define HEADS 8
#define HEAD_DIM 32
#define M_TOT 512
// softmax-scale folded with log2(e) so exp(x) == exp2(S)
#define QSCALE (0.17677669529663687f * 1.4426950408889634f)

typedef float f32x16 __attribute__((ext_vector_type(16)));
typedef short bf16x8 __attribute__((ext_vector_type(8)));

union BF8 { bf16x8 v; unsigned u[4]; uint2 u2[2]; };

// RNE packed f32x2 -> bf16x2 (lowers to v_cvt_pk_bf16_f32)
__device__ __forceinline__ unsigned cvt2(float lo, float hi) {
    __hip_bfloat162 h = __float22bfloat162_rn(make_float2(lo, hi));
    union { __hip_bfloat162 h2; unsigned u; } un;
    un.h2 = h;
    return un.u;
}

// k_sum[bh][m][c] = sum_hq k[b, hq*512+m, head*32+c]  -> bf16 in ws
__global__ __launch_bounds__(256) void ksum_kernel(const float* __restrict__ k,
                                                   unsigned short* __restrict__ ks) {
    const int blk = blockIdx.x;          // 1024 = bh(64) x part(16)
    const int bh = blk >> 4, part = blk & 15;
    const int b = bh >> 3, head = bh & 7;
    const float* kb = k + (size_t)b * L_TOT * DIM + head * HEAD_DIM;
    const int c0 = (threadIdx.x & 7) * 4;          // 4-float col group
    const int m = part * 32 + (threadIdx.x >> 3);  // [0,512)
    float4 s = make_float4(0.f, 0.f, 0.f, 0.f);
#pragma unroll
    for (int hq = 0; hq < 8; ++hq) {
        const float4 f = *(const float4*)(kb + (size_t)(hq * 512 + m) * DIM + c0);
        s.x += f.x; s.y += f.y; s.z += f.z; s.w += f.w;
    }
    uint2 o;
    o.x = cvt2(s.x, s.y);
    o.y = cvt2(s.z, s.w);
    *(uint2*)(ks + ((size_t)bh * M_TOT + m) * HEAD_DIM + c0) = o;
}

// One block per (bh, h, half). 8 waves, each wave owns 32 q-rows.
// S^T = mfma(ksum, q) (lane = qrow), exp2 (no max-subtract), P->bf16 via
// cvt_pk + permlane32_swap, O = mfma(P, vT). ks A-frags software-pipelined
// 1 chunk ahead from global (L2-resident 2MB).
template <bool USE_WS>
__global__ __launch_bounds__(512, 4) void attn_kernel(const float* __restrict__ q,
                                                      const float* __restrict__ kg,
                                                      const float* __restrict__ v,
                                                      const unsigned short* __restrict__ ks,
                                                      float* __restrict__ out) {
    // LDS (shorts): vT[32][516] | inv[8][32] floats | (fallback) KS[512][36]
    constexpr int VT_SH = 32 * 516;   // 16512 shorts
    constexpr int INV_SH = 8 * 32 * 2;
    __shared__ unsigned short smem[USE_WS ? (VT_SH + INV_SH) : (VT_SH + INV_SH + 512 * 36)];
    unsigned short* vT = smem;

    const int tid = threadIdx.x;
    const int wave = tid >> 6;
    const int lane = tid & 63;
    const int ql = lane & 31;
    const int hi = lane >> 5;

    // XCD-aware swizzle (1024 % 8 == 0 -> bijective)
    const int bid = blockIdx.x;
    const int wk = (bid & 7) * 128 + (bid >> 3);
    const int bh = wk >> 4, h = (wk >> 1) & 7, half = wk & 1;
    const int b = bh >> 3, head = bh & 7;

    const float* vbase = v + ((size_t)b * L_TOT + h * M_TOT) * DIM + head * HEAD_DIM;

    // ---- stage V transposed (bf16) ----
#pragma unroll
    for (int it = 0; it < 8; ++it) {
        const int idx = it * 512 + tid;      // [0, 4096)
        const int m = idx >> 3, c0 = (idx & 7) * 4;
        const float4 f = *(const float4*)(vbase + (size_t)m * DIM + c0);
        const unsigned w0 = cvt2(f.x, f.y), w1 = cvt2(f.z, f.w);
        vT[(c0 + 0) * 516 + m] = (unsigned short)w0;
        vT[(c0 + 1) * 516 + m] = (unsigned short)(w0 >> 16);
        vT[(c0 + 2) * 516 + m] = (unsigned short)w1;
        vT[(c0 + 3) * 516 + m] = (unsigned short)(w1 >> 16);
    }
    unsigned short* KS = smem + VT_SH + INV_SH;
    if (!USE_WS) {
        const float* kb = kg + (size_t)b * L_TOT * DIM + head * HEAD_DIM;
        for (int idx = tid; idx < M_TOT * HEAD_DIM; idx += 512) {
            const int m = idx >> 5, c = idx & 31;
            float s = 0.f;
#pragma unroll
            for (int hq = 0; hq < 8; ++hq)
                s += kb[(size_t)(hq * 512 + m) * DIM + c];
            KS[m * 36 + c] = (unsigned short)cvt2(s, 0.f);
        }
    }
    __syncthreads();

    // ---- this wave's 32 q-rows ----
    const int g = half * 8 + wave;           // [0,16)
    const int wcol = g >> 1, n0 = (g & 1) * 32;
    const int n = n0 + ql;
    const int Lq = (h * 8 + (n >> 3)) * 64 + wcol * 8 + (n & 7);
    const float* qp = q + ((size_t)b * L_TOT + Lq) * DIM + head * HEAD_DIM;

    BF8 qf0, qf1;  // B-frag: col = qrow = ql, k(c) = 16*half_k + 8*hi + j
    {
        const float4 f0 = *(const float4*)(qp + 8 * hi);
        const float4 f1 = *(const float4*)(qp + 8 * hi + 4);
        qf0.u[0] = cvt2(f0.x * QSCALE, f0.y * QSCALE);
        qf0.u[1] = cvt2(f0.z * QSCALE, f0.w * QSCALE);
        qf0.u[2] = cvt2(f1.x * QSCALE, f1.y * QSCALE);
        qf0.u[3] = cvt2(f1.z * QSCALE, f1.w * QSCALE);
        const float4 f2 = *(const float4*)(qp + 16 + 8 * hi);
        const float4 f3 = *(const float4*)(qp + 16 + 8 * hi + 4);
        qf1.u[0] = cvt2(f2.x * QSCALE, f2.y * QSCALE);
        qf1.u[1] = cvt2(f2.z * QSCALE, f2.w * QSCALE);
        qf1.u[2] = cvt2(f3.x * QSCALE, f3.y * QSCALE);
        qf1.u[3] = cvt2(f3.z * QSCALE, f3.w * QSCALE);
    }

    const unsigned short* ksb = ks + (size_t)bh * (M_TOT * HEAD_DIM);
    const unsigned short* vb0 = vT + ql * 516 + 8 * hi;
    float* invW = (float*)(smem + VT_SH) + wave * 32;

    f32x16 O;
#pragma unroll
    for (int r = 0; r < 16; ++r) O[r] = 0.f;
    float lsum = 0.f;

    BF8 a0, a1, b0, b1;
    if (USE_WS) {
        a0.v = *(const bf16x8*)(ksb + (size_t)ql * 32 + 8 * hi);
        a1.v = *(const bf16x8*)(ksb + (size_t)ql * 32 + 16 + 8 * hi);
    }

    // one chunk of 32 m: consume c0/c1, prefetch chunk at M0n into p0/p1
    auto body = [&](int M0, BF8& c0, BF8& c1, BF8& p0, BF8& p1, int M0n) {
        if (USE_WS) {
            p0.v = *(const bf16x8*)(ksb + (size_t)(M0n + ql) * 32 + 8 * hi);
            p1.v = *(const bf16x8*)(ksb + (size_t)(M0n + ql) * 32 + 16 + 8 * hi);
        } else {
            const unsigned short* kr = KS + (M0 + ql) * 36 + 8 * hi;
            c0.u2[0] = *(const uint2*)(kr);
            c0.u2[1] = *(const uint2*)(kr + 4);
            c1.u2[0] = *(const uint2*)(kr + 16);
            c1.u2[1] = *(const uint2*)(kr + 20);
        }
        f32x16 S;
#pragma unroll
        for (int r = 0; r < 16; ++r) S[r] = 0.f;
        S = __builtin_amdgcn_mfma_f32_32x32x16_bf16(c0.v, qf0.v, S, 0, 0, 0);
        S = __builtin_amdgcn_mfma_f32_32x32x16_bf16(c1.v, qf1.v, S, 0, 0, 0);

        // V B-frag loads early so LDS latency hides under exp2
        BF8 VB0, VB1;  // col = c_out = ql, k(m) = M0 + 16*kt + 8*hi + j
        const unsigned short* vb = vb0 + M0;
        VB0.u2[0] = *(const uint2*)(vb);
        VB0.u2[1] = *(const uint2*)(vb + 4);
        VB1.u2[0] = *(const uint2*)(vb + 16);
        VB1.u2[1] = *(const uint2*)(vb + 20);

        // p = exp2(S); lane's reg r is m = M0 + (r&3) + 8*(r>>2) + 4*hi, col = qrow
        float p[16];
#pragma unroll
        for (int r = 0; r < 16; ++r) p[r] = __builtin_amdgcn_exp2f(S[r]);
#pragma unroll
        for (int r = 0; r < 16; ++r) lsum += p[r];

        unsigned w0 = cvt2(p[0], p[1]),   w1 = cvt2(p[2], p[3]);
        unsigned w2 = cvt2(p[4], p[5]),   w3 = cvt2(p[6], p[7]);
        unsigned w4 = cvt2(p[8], p[9]),   w5 = cvt2(p[10], p[11]);
        unsigned w6 = cvt2(p[12], p[13]), w7 = cvt2(p[14], p[15]);
        // vdst.row1 <-> vsrc.row0: builds A-frag words (k = m ascending) in-register
        asm("v_permlane32_swap_b32 %0, %1" : "+v"(w0), "+v"(w2));
        asm("v_permlane32_swap_b32 %0, %1" : "+v"(w1), "+v"(w3));
        asm("v_permlane32_swap_b32 %0, %1" : "+v"(w4), "+v"(w6));
        asm("v_permlane32_swap_b32 %0, %1" : "+v"(w5), "+v"(w7));
        BF8 PA0, PA1;
        PA0.u[0] = w0; PA0.u[1] = w1; PA0.u[2] = w2; PA0.u[3] = w3;
        PA1.u[0] = w4; PA1.u[1] = w5; PA1.u[2] = w6; PA1.u[3] = w7;
        O = __builtin_amdgcn_mfma_f32_32x32x16_bf16(PA0.v, VB0.v, O, 0, 0, 0);
        O = __builtin_amdgcn_mfma_f32_32x32x16_bf16(PA1.v, VB1.v, O, 0, 0, 0);
    };

    for (int i = 0; i < 8; ++i) {
        const int M0 = i * 64;
        body(M0,      a0, a1, b0, b1, M0 + 32);
        body(M0 + 32, b0, b1, a0, a1, (M0 + 64) & 511);
    }

    // row-sum across the two k-halves; redistribute 1/l via per-wave LDS broadcast
    lsum += __shfl_xor(lsum, 32, 64);
    const float inv = __builtin_amdgcn_rcpf(lsum);
    if (hi == 0) invW[ql] = inv;  // inv for qrow = ql

    // O: col = c_out = ql, row(r) = (r&3) + 8*(r>>2) + 4*hi -> coalesced stores
    const int rowBase = h * 512 + (n0 >> 3) * 64 + wcol * 8 + 4 * hi;
    float* ob = out + ((size_t)b * L_TOT + rowBase) * DIM + head * HEAD_DIM + ql;
#pragma unroll
    for (int t = 0; t < 4; ++t) {
        const float4 iv = *(const float4*)(invW + 8 * t + 4 * hi);  // rows 8t+4hi..+3
        ob[(size_t)(t * 64 + 0) * DIM] = O[4 * t + 0] * iv.x;
        ob[(size_t)(t * 64 + 1) * DIM] = O[4 * t + 1] * iv.y;
        ob[(size_t)(t * 64 + 2) * DIM] = O[4 * t + 2] * iv.z;
        ob[(size_t)(t * 64 + 3) * DIM] = O[4 * t + 3] * iv.w;
    }
}

extern "C" void kernel_launch(void* const* d_in, const int* in_sizes, int n_in,
                              void* d_out, int out_size, void* d_ws, size_t ws_size,
                              hipStream_t stream) {
    const float* qkv = (const float*)d_in[0];
    const float* q = qkv;
    const float* k = qkv + (size_t)NB * L_TOT * DIM;
    const float* v = qkv + (size_t)2 * NB * L_TOT * DIM;
    float* out = (float*)d_out;
    const size_t ks_bytes = (size_t)NB * HEADS * M_TOT * HEAD_DIM * 2;  // 2 MB
    if (ws_size >= ks_bytes) {
        unsigned short* ks = (unsigned short*)d_ws;
        ksum_kernel<<<dim3(1024), dim3(256), 0, stream>>>(k, ks);
        attn_kernel<true><<<dim3(1024), dim3(512), 0, stream>>>(q, k, v, ks, out);
    } else {
        attn_kernel<false><<<dim3(1024), dim3(512), 0, stream>>>(q, k, v, nullptr, out);
    }
}

// Round 4
// 174.170 us; speedup vs baseline: 1.2009x; 1.0048x over previous
//
#include <hip/hip_runtime.h>
#include <hip/hip_bf16.h>

#define NB 8
#define L_TOT 4096
#define DIM 256
#define HEADS 8
#define HEAD_DIM 32
#define M_TOT 512
// softmax-scale folded with log2(e) so exp(x) == exp2(S)
#define QSCALE (0.17677669529663687f * 1.4426950408889634f)

typedef float f32x16 __attribute__((ext_vector_type(16)));
typedef short bf16x8 __attribute__((ext_vector_type(8)));

union BF8 { bf16x8 v; unsigned u[4]; uint2 u2[2]; uint4 u4; };

// RNE packed f32x2 -> bf16x2 (lowers to v_cvt_pk_bf16_f32)
__device__ __forceinline__ unsigned cvt2(float lo, float hi) {
    __hip_bfloat162 h = __float22bfloat162_rn(make_float2(lo, hi));
    union { __hip_bfloat162 h2; unsigned u; } un;
    un.h2 = h;
    return un.u;
}

// Frag-ready k_sum layout ("ksF"), 16384 shorts per bh:
//   element (m, c) at: (m>>5)*1024 + (c>=16)*512 + ((m&31) + 32*((c>>3)&1))*8 + (c&7)
// so MFMA A-frag for chunk ch is a linear ds_read_b128 at lane*16.
__global__ __launch_bounds__(256) void ksum_kernel(const float* __restrict__ k,
                                                   unsigned short* __restrict__ ks) {
    const int blk = blockIdx.x;          // 1024 = bh(64) x part(16)
    const int bh = blk >> 4, part = blk & 15;
    const int b = bh >> 3, head = bh & 7;
    const float* kb = k + (size_t)b * L_TOT * DIM + head * HEAD_DIM;
    const int c0 = (threadIdx.x & 7) * 4;          // 4-float col group
    const int m = part * 32 + (threadIdx.x >> 3);  // [0,512)
    float4 s = make_float4(0.f, 0.f, 0.f, 0.f);
#pragma unroll
    for (int hq = 0; hq < 8; ++hq) {
        const float4 f = *(const float4*)(kb + (size_t)(hq * 512 + m) * DIM + c0);
        s.x += f.x; s.y += f.y; s.z += f.z; s.w += f.w;
    }
    uint2 o;
    o.x = cvt2(s.x, s.y);
    o.y = cvt2(s.z, s.w);
    const int lane = (m & 31) + 32 * ((c0 >> 3) & 1);
    const size_t off = (size_t)bh * 16384 + (size_t)(m >> 5) * 1024 +
                       (c0 >= 16 ? 512 : 0) + lane * 8 + (c0 & 7);
    *(uint2*)(ks + off) = o;
}

// One block per (bh, h). 8 waves x 2 groups of 32 q-rows.
// ksF + vF staged in LDS in frag-linear order (conflict-free b128 reads).
// Cross-chunk pipeline: QK(ch+1) issued before softmax/PV(ch).
template <bool USE_WS>
__global__ __launch_bounds__(512, 4) void attn_kernel(const float* __restrict__ q,
                                                      const float* __restrict__ kg,
                                                      const float* __restrict__ v,
                                                      const unsigned short* __restrict__ ks,
                                                      float* __restrict__ out) {
    // shorts: vF[16384] | ksF[16384] | inv[8*32] floats
    constexpr int KSF_OFF = 16384;
    constexpr int INV_OFF = 32768;
    __shared__ unsigned short smem[33280];
    unsigned short* vF = smem;
    unsigned short* ksF = smem + KSF_OFF;

    const int tid = threadIdx.x;
    const int wave = tid >> 6;
    const int lane = tid & 63;
    const int ql = lane & 31;
    const int hi = lane >> 5;

    // XCD-aware swizzle (512 % 8 == 0 -> bijective)
    const int bid = blockIdx.x;
    const int wk = (bid & 7) * 64 + (bid >> 3);
    const int bh = wk >> 3, h = wk & 7;
    const int b = bh >> 3, head = bh & 7;

    // ---- stage ksF (32KB linear copy; reg-staged, b128 LDS writes) ----
    if (USE_WS) {
        const uint4* ksrc4 = (const uint4*)(ks + (size_t)bh * 16384);
        uint4* kdst4 = (uint4*)ksF;
        const uint4 t0 = ksrc4[tid], t1 = ksrc4[512 + tid];
        const uint4 t2 = ksrc4[1024 + tid], t3 = ksrc4[1536 + tid];
        kdst4[tid] = t0; kdst4[512 + tid] = t1;
        kdst4[1024 + tid] = t2; kdst4[1536 + tid] = t3;
    } else {
        const float* kb = kg + (size_t)b * L_TOT * DIM + head * HEAD_DIM;
#pragma unroll
        for (int it = 0; it < 8; ++it) {
            const int idx = it * 512 + tid;            // [0,4096)
            const int m = idx >> 3, c0 = (idx & 7) * 4;
            float4 s = make_float4(0.f, 0.f, 0.f, 0.f);
#pragma unroll
            for (int hq = 0; hq < 8; ++hq) {
                const float4 f = *(const float4*)(kb + (size_t)(hq * 512 + m) * DIM + c0);
                s.x += f.x; s.y += f.y; s.z += f.z; s.w += f.w;
            }
            uint2 o; o.x = cvt2(s.x, s.y); o.y = cvt2(s.z, s.w);
            const int ln = (m & 31) + 32 * ((c0 >> 3) & 1);
            *(uint2*)(ksF + (m >> 5) * 1024 + (c0 >= 16 ? 512 : 0) + ln * 8 + (c0 & 7)) = o;
        }
    }

    // ---- stage vF: frag-linear  (element (m,c) -> (m>>5)*1024 + ((m>>4)&1)*512
    //                               + ((c + 32*((m>>3)&1))*8 + (m&7)) ----
    const float* vbase = v + ((size_t)b * L_TOT + h * M_TOT) * DIM + head * HEAD_DIM;
#pragma unroll
    for (int it = 0; it < 8; ++it) {
        const int idx = it * 512 + tid;      // [0, 4096)
        const int m = idx >> 3, c0 = (idx & 7) * 4;
        const float4 f = *(const float4*)(vbase + (size_t)m * DIM + c0);
        const unsigned w0 = cvt2(f.x, f.y), w1 = cvt2(f.z, f.w);
        unsigned short* bp = vF + (m >> 5) * 1024 + ((m >> 4) & 1) * 512 +
                             (c0 + 32 * ((m >> 3) & 1)) * 8 + (m & 7);
        bp[0]  = (unsigned short)w0;
        bp[8]  = (unsigned short)(w0 >> 16);
        bp[16] = (unsigned short)w1;
        bp[24] = (unsigned short)(w1 >> 16);
    }
    __syncthreads();

    const unsigned short* ksW = ksF + lane * 8;
    const unsigned short* vfW = vF + lane * 8;
    float* invW = (float*)(smem + INV_OFF) + wave * 32;
    const float* qbase = q + (size_t)b * L_TOT * DIM + head * HEAD_DIM;

    for (int gi = 0; gi < 2; ++gi) {
        const int wcol = wave, n0 = gi * 32;
        const int n = n0 + ql;
        const int Lq = (h * 8 + (n >> 3)) * 64 + wcol * 8 + (n & 7);
        const float* qp = qbase + (size_t)Lq * DIM;

        BF8 qf0, qf1;  // B-frag: col = qrow = ql, k(c) = 16*sec + 8*hi + j
        {
            const float4 f0 = *(const float4*)(qp + 8 * hi);
            const float4 f1 = *(const float4*)(qp + 8 * hi + 4);
            qf0.u[0] = cvt2(f0.x * QSCALE, f0.y * QSCALE);
            qf0.u[1] = cvt2(f0.z * QSCALE, f0.w * QSCALE);
            qf0.u[2] = cvt2(f1.x * QSCALE, f1.y * QSCALE);
            qf0.u[3] = cvt2(f1.z * QSCALE, f1.w * QSCALE);
            const float4 f2 = *(const float4*)(qp + 16 + 8 * hi);
            const float4 f3 = *(const float4*)(qp + 16 + 8 * hi + 4);
            qf1.u[0] = cvt2(f2.x * QSCALE, f2.y * QSCALE);
            qf1.u[1] = cvt2(f2.z * QSCALE, f2.w * QSCALE);
            qf1.u[2] = cvt2(f3.x * QSCALE, f3.y * QSCALE);
            qf1.u[3] = cvt2(f3.z * QSCALE, f3.w * QSCALE);
        }

        f32x16 O;
#pragma unroll
        for (int r = 0; r < 16; ++r) O[r] = 0.f;
        float lsum = 0.f;

        // QK for one chunk: S^T = ksF(A) x q(B)
        auto qk = [&](int ch) -> f32x16 {
            BF8 A0, A1;
            A0.u4 = *(const uint4*)(ksW + ch * 1024);
            A1.u4 = *(const uint4*)(ksW + ch * 1024 + 512);
            f32x16 z;
#pragma unroll
            for (int r = 0; r < 16; ++r) z[r] = 0.f;
            f32x16 S = __builtin_amdgcn_mfma_f32_32x32x16_bf16(A0.v, qf0.v, z, 0, 0, 0);
            return __builtin_amdgcn_mfma_f32_32x32x16_bf16(A1.v, qf1.v, S, 0, 0, 0);
        };

        // softmax (exp2, no max-subtract) + PV for one chunk
        auto smPV = [&](const f32x16& S, int ch) {
            BF8 VB0, VB1;
            VB0.u4 = *(const uint4*)(vfW + ch * 1024);
            VB1.u4 = *(const uint4*)(vfW + ch * 1024 + 512);
            float p[16];
#pragma unroll
            for (int r = 0; r < 16; ++r) p[r] = __builtin_amdgcn_exp2f(S[r]);
            // pairwise tree for lsum
            const float s0 = (p[0] + p[1]) + (p[2] + p[3]);
            const float s1 = (p[4] + p[5]) + (p[6] + p[7]);
            const float s2 = (p[8] + p[9]) + (p[10] + p[11]);
            const float s3 = (p[12] + p[13]) + (p[14] + p[15]);
            lsum += (s0 + s1) + (s2 + s3);

            unsigned w0 = cvt2(p[0], p[1]),   w1 = cvt2(p[2], p[3]);
            unsigned w2 = cvt2(p[4], p[5]),   w3 = cvt2(p[6], p[7]);
            unsigned w4 = cvt2(p[8], p[9]),   w5 = cvt2(p[10], p[11]);
            unsigned w6 = cvt2(p[12], p[13]), w7 = cvt2(p[14], p[15]);
            // vdst.row1 <-> vsrc.row0: builds P A-frag words (k = m ascending)
            asm("v_permlane32_swap_b32 %0, %1" : "+v"(w0), "+v"(w2));
            asm("v_permlane32_swap_b32 %0, %1" : "+v"(w1), "+v"(w3));
            asm("v_permlane32_swap_b32 %0, %1" : "+v"(w4), "+v"(w6));
            asm("v_permlane32_swap_b32 %0, %1" : "+v"(w5), "+v"(w7));
            BF8 PA0, PA1;
            PA0.u[0] = w0; PA0.u[1] = w1; PA0.u[2] = w2; PA0.u[3] = w3;
            PA1.u[0] = w4; PA1.u[1] = w5; PA1.u[2] = w6; PA1.u[3] = w7;
            O = __builtin_amdgcn_mfma_f32_32x32x16_bf16(PA0.v, VB0.v, O, 0, 0, 0);
            O = __builtin_amdgcn_mfma_f32_32x32x16_bf16(PA1.v, VB1.v, O, 0, 0, 0);
        };

        // cross-chunk pipeline: QK(ch+1) issued before softmax/PV(ch)
        f32x16 Sc = qk(0);
        for (int ch = 0; ch < 15; ++ch) {
            f32x16 Sn = qk(ch + 1);
            smPV(Sc, ch);
            Sc = Sn;
        }
        smPV(Sc, 15);

        // row-sum across the two k-halves; redistribute 1/l via per-wave LDS
        lsum += __shfl_xor(lsum, 32, 64);
        const float inv = __builtin_amdgcn_rcpf(lsum);
        if (hi == 0) invW[ql] = inv;  // inv for qrow = ql

        // O: col = c_out = ql, row(r) = (r&3) + 8*(r>>2) + 4*hi -> coalesced stores
        const int rowBase = h * 512 + (n0 >> 3) * 64 + wcol * 8 + 4 * hi;
        float* ob = out + ((size_t)b * L_TOT + rowBase) * DIM + head * HEAD_DIM + ql;
#pragma unroll
        for (int t = 0; t < 4; ++t) {
            const float4 iv = *(const float4*)(invW + 8 * t + 4 * hi);
            ob[(size_t)(t * 64 + 0) * DIM] = O[4 * t + 0] * iv.x;
            ob[(size_t)(t * 64 + 1) * DIM] = O[4 * t + 1] * iv.y;
            ob[(size_t)(t * 64 + 2) * DIM] = O[4 * t + 2] * iv.z;
            ob[(size_t)(t * 64 + 3) * DIM] = O[4 * t + 3] * iv.w;
        }
    }
}

extern "C" void kernel_launch(void* const* d_in, const int* in_sizes, int n_in,
                              void* d_out, int out_size, void* d_ws, size_t ws_size,
                              hipStream_t stream) {
    const float* qkv = (const float*)d_in[0];
    const float* q = qkv;
    const float* k = qkv + (size_t)NB * L_TOT * DIM;
    const float* v = qkv + (size_t)2 * NB * L_TOT * DIM;
    float* out = (float*)d_out;
    const size_t ks_bytes = (size_t)NB * HEADS * M_TOT * HEAD_DIM * 2;  // 2 MB
    if (ws_size >= ks_bytes) {
        unsigned short* ks = (unsigned short*)d_ws;
        ksum_kernel<<<dim3(1024), dim3(256), 0, stream>>>(k, ks);
        attn_kernel<true><<<dim3(512), dim3(512), 0, stream>>>(q, k, v, ks, out);
    } else {
        attn_kernel<false><<<dim3(512), dim3(512), 0, stream>>>(q, k, v, nullptr, out);
    }
}